// Round 8
// baseline (1223.810 us; speedup 1.0000x reference)
//
#include <hip/hip_runtime.h>
#include <hip/hip_bf16.h>

typedef unsigned char u8;
typedef unsigned short u16;
typedef unsigned int u32;
typedef __attribute__((ext_vector_type(4))) int i32x4;
typedef __attribute__((ext_vector_type(8))) int i32x8;
typedef __attribute__((ext_vector_type(4))) float f32x4;

#define GLD16(g, l) __builtin_amdgcn_global_load_lds((const __attribute__((address_space(1))) u32*)(g), (__attribute__((address_space(3))) u32*)(l), 16, 0, 0)
#define SCALE1 0x7F7F7F7F   // E8M0 exponent 127 = 2^0 for all blocks

__device__ __forceinline__ u32 flipf(float f) {
    u32 u = __float_as_uint(f);
    return (u >> 31) ? ~u : (u | 0x80000000u);
}

__device__ __forceinline__ float unflipf(u32 k) {
    return __uint_as_float((k >> 31) ? (k ^ 0x80000000u) : ~k);
}

// pack 4 floats -> 4 fp8 e4m3 (OCP) bytes
__device__ __forceinline__ u32 pk4_fp8(float a, float b, float c, float d) {
    u32 r = (u32)__builtin_amdgcn_cvt_pk_fp8_f32(a, b, 0, false);
    r = (u32)__builtin_amdgcn_cvt_pk_fp8_f32(c, d, (int)r, true);
    return r;
}

// bilinear 14->28 taps (jax.image.resize, half-pixel, edge-renormalized)
__device__ __forceinline__ void taps(int o, int& i0, int& i1, float& w0, float& w1) {
    int k = (o - 1) >> 1;
    float fy = (0.5f * (float)o - 0.25f) - (float)k;
    i0 = k; i1 = k + 1;
    w0 = 1.0f - fy; w1 = fy;
    if (i0 < 0)  { i0 = 0;  w0 = 0.0f; w1 = 1.0f; }
    if (i1 > 13) { i1 = 13; w1 = 0.0f; w0 = 1.0f; }
}

// merged: [blocks 0..16383] memory-bank fp32->fp8 + norms (+minkey init)
//         [blocks 16384..19519] U = 3x3 box-sum of paired feat3 channels
__global__ __launch_bounds__(256) void prep_kernel(
    const float* __restrict__ f3, float* __restrict__ U,
    const float* __restrict__ mb, u8* __restrict__ mbb, float* __restrict__ mb2,
    u32* __restrict__ minkey) {
    int bid = blockIdx.x, tid = threadIdx.x;
    if (bid < 16384) {
        float4 v = ((const float4*)(mb + (size_t)bid * 1024))[tid];
        ((u32*)(mbb + (size_t)bid * 1024))[tid] = pk4_fp8(v.x, v.y, v.z, v.w);
        float ssq = v.x * v.x + v.y * v.y + v.z * v.z + v.w * v.w;
        for (int s = 32; s; s >>= 1) ssq += __shfl_down(ssq, s);
        __shared__ float sm[4];
        if ((tid & 63) == 0) sm[tid >> 6] = ssq;
        __syncthreads();
        if (tid == 0) mb2[bid] = sm[0] + sm[1] + sm[2] + sm[3];
        if (bid < 25) {
            int i = bid * 256 + tid;
            if (i < 6400) minkey[i] = 0xFFFFFFFFu;
        }
    } else {
        int idx = (bid - 16384) * 256 + tid;
        if (idx >= 8 * 512 * 196) return;
        int b = idx / (512 * 196);
        int rem = idx % (512 * 196);
        int t = rem / 196;
        int yx = rem % 196;
        int y = yx / 14, x = yx % 14;
        const float* p0 = f3 + ((size_t)(b * 1024 + 2 * t)) * 196;
        const float* p1 = p0 + 196;
        float s = 0.f;
        #pragma unroll
        for (int dy = -1; dy <= 1; ++dy) {
            int yy = y + dy; if ((unsigned)yy >= 14u) continue;
            #pragma unroll
            for (int dx = -1; dx <= 1; ++dx) {
                int xx = x + dx; if ((unsigned)xx >= 14u) continue;
                s += p0[yy * 14 + xx] + p1[yy * 14 + xx];
            }
        }
        U[idx] = s;
    }
}

// q[n, 0:512] = weighted 3x3 mean of feat2; q[n, 512+t] = bilinear(U)[h,w]/18
// thread handles 4 CONSECUTIVE dims -> one packed u32 fp8 store.
__global__ __launch_bounds__(256) void q_kernel(const float* __restrict__ feat2, const float* __restrict__ U,
                                                u8* __restrict__ qb, float* __restrict__ qn2) {
    int n = blockIdx.x;
    int b = n / 784;
    int hw = n % 784;
    int h = hw / 28, w = hw % 28;
    int tid = threadIdx.x;
    int y0, y1, x0, x1; float wy0, wy1, wx0, wx1;
    taps(h, y0, y1, wy0, wy1);
    taps(w, x0, x1, wx0, wx1);
    int d0 = tid * 4;
    float vals[4];
    if (d0 < 512) {
        #pragma unroll
        for (int j = 0; j < 4; ++j) {
            const float* p = feat2 + ((size_t)(b * 512 + d0 + j)) * 784;
            float s = 0.f;
            #pragma unroll
            for (int di = -1; di <= 1; ++di) {
                int y = h + di; if ((unsigned)y >= 28u) continue;
                #pragma unroll
                for (int dj = -1; dj <= 1; ++dj) {
                    int x = w + dj; if ((unsigned)x >= 28u) continue;
                    float v = p[y * 28 + x];
                    s += (di == 0 && dj == 0) ? 2.f * v : v;
                }
            }
            vals[j] = s * 0.1f;
        }
    } else {
        #pragma unroll
        for (int j = 0; j < 4; ++j) {
            const float* up = U + ((size_t)(b * 512 + (d0 - 512 + j))) * 196;
            float v00 = up[y0 * 14 + x0], v01 = up[y0 * 14 + x1];
            float v10 = up[y1 * 14 + x0], v11 = up[y1 * 14 + x1];
            vals[j] = (wy0 * (wx0 * v00 + wx1 * v01) + wy1 * (wx0 * v10 + wx1 * v11)) * (1.f / 18.f);
        }
    }
    ((u32*)(qb + (size_t)n * 1024))[tid] = pk4_fp8(vals[0], vals[1], vals[2], vals[3]);
    float ssq = vals[0] * vals[0] + vals[1] * vals[1] + vals[2] * vals[2] + vals[3] * vals[3];
    for (int s = 32; s; s >>= 1) ssq += __shfl_down(ssq, s);
    __shared__ float sm[4];
    if ((tid & 63) == 0) sm[tid >> 6] = ssq;
    __syncthreads();
    if (tid == 0) qn2[n] = sm[0] + sm[1] + sm[2] + sm[3];
}

// 256x256-tile BK=128 FP8 MFMA-scale GEMM (mfma_scale_f32_16x16x128_f8f6f4,
// constant 1.0 block scales => plain fp8 at MX rate). Burst schedule from R6:
// all 24 frag ds_reads + all 8 next-tile global_load_lds up front, counted
// lgkmcnt(12)/(4)/(0) gates, 1 barrier + 1 vmcnt per tile. Fused min epilogue.
// M=6400 (q rows, 6272 real), N=16384, K=1024 -> 8 K-tiles.
__global__ __launch_bounds__(512, 1) void gemm_min_kernel(
    const u8* __restrict__ qb, const u8* __restrict__ mbb,
    const float* __restrict__ qn2, const float* __restrict__ mb2,
    u32* __restrict__ minkeys) {
    __shared__ __align__(16) u8 As[2][32768];   // [buf][256 rows x 128 B]
    __shared__ __align__(16) u8 Bs[2][32768];
    __shared__ u32 rowmin[256];

    const int tid = threadIdx.x;
    const int wid = tid >> 6;
    const int lane = tid & 63;
    const int wm = wid >> 2;   // 2 M-waves
    const int wn = wid & 3;    // 4 N-waves

    // XCD-aware bijective swizzle: 1600 blocks, 8 XCDs, 200/XCD.
    const int flat = blockIdx.x;
    const int swz = (flat & 7) * 200 + (flat >> 3);
    const int q0 = (swz % 25) * 256;   // q-row (M) panel
    const int m0 = (swz / 25) * 256;   // memory-bank (N) panel

    // staging: half-tile = 128 rows x 128 B = 16 KB; 2 gload_lds/thread.
    // LDS dest linear; global source 16B-slot XOR-swizzled with row&7.
    const int rA = wid * 16 + (lane >> 3);            // + j*8
    const int srcslot = (lane & 7) ^ (lane >> 3);
    size_t baseA[2], baseB[2];
    u32 ldst[2];
    #pragma unroll
    for (int j = 0; j < 2; ++j) {
        baseA[j] = (size_t)(q0 + rA + j * 8) * 1024 + srcslot * 16;
        baseB[j] = (size_t)(m0 + rA + j * 8) * 1024 + srcslot * 16;
        ldst[j] = (wid * 2 + j) * 1024;               // byte idx, wave-uniform
    }

    #define STAGE_A(T, H) { const int _t = (T), _h = (H); \
        GLD16(qb + baseA[0] + (size_t)_h * 131072 + _t * 128, &As[_t & 1][_h * 16384 + ldst[0]]); \
        GLD16(qb + baseA[1] + (size_t)_h * 131072 + _t * 128, &As[_t & 1][_h * 16384 + ldst[1]]); }
    #define STAGE_B(T, H) { const int _t = (T), _h = (H); \
        GLD16(mbb + baseB[0] + (size_t)_h * 131072 + _t * 128, &Bs[_t & 1][_h * 16384 + ldst[0]]); \
        GLD16(mbb + baseB[1] + (size_t)_h * 131072 + _t * 128, &Bs[_t & 1][_h * 16384 + ldst[1]]); }

    // fragment read addressing (byte offsets; row&7 == lane&7 for all frags)
    const u32 arow = (u32)(wm * 128 + (lane & 15)) * 128;   // + m*2048
    const u32 brow = (u32)(wn * 64 + (lane & 15)) * 128;    // + n*2048
    const u32 sl0 = (u32)((((lane >> 4) * 2 + 0) ^ (lane & 7)) * 16);  // k bytes 0-15 of lane's 32
    const u32 sl1 = (u32)((((lane >> 4) * 2 + 1) ^ (lane & 7)) * 16);  // k bytes 16-31

    #define RD_FRAG(DST, BASE, OFF) { \
        i32x4 _lo = *(const i32x4*)((BASE) + (OFF) + sl0); \
        i32x4 _hi = *(const i32x4*)((BASE) + (OFF) + sl1); \
        DST = __builtin_shufflevector(_lo, _hi, 0, 1, 2, 3, 4, 5, 6, 7); }

    f32x4 acc[8][4] = {};
    i32x8 alo[4], ahi[4], b01[2], b23[2];

    #define MFMA_Q(M0, AARR, BARR, N0) \
        _Pragma("unroll") for (int m = 0; m < 4; ++m) \
            _Pragma("unroll") for (int n = 0; n < 2; ++n) \
                acc[(M0) + m][(N0) + n] = __builtin_amdgcn_mfma_scale_f32_16x16x128_f8f6f4( \
                    AARR[m], BARR[n], acc[(M0) + m][(N0) + n], 0, 0, 0, SCALE1, 0, SCALE1);

    // ---- prologue: stage tile 0, wait, barrier
    STAGE_A(0, 0); STAGE_A(0, 1);
    STAGE_B(0, 0); STAGE_B(0, 1);
    asm volatile("s_waitcnt vmcnt(0)" ::: "memory");
    __builtin_amdgcn_s_barrier();
    __builtin_amdgcn_sched_barrier(0);

    for (int t = 0; t < 8; ++t) {
        const u8* Ab = &As[t & 1][0];
        const u8* Bb = &Bs[t & 1][0];

        // ---- burst: all 24 frag reads, in lgkm-count order alo,b01,ahi,b23
        #pragma unroll
        for (int m = 0; m < 4; ++m) RD_FRAG(alo[m], Ab, arow + m * 2048)
        #pragma unroll
        for (int n = 0; n < 2; ++n) RD_FRAG(b01[n], Bb, brow + n * 2048)
        #pragma unroll
        for (int m = 0; m < 4; ++m) RD_FRAG(ahi[m], Ab, arow + (4 + m) * 2048)
        #pragma unroll
        for (int n = 0; n < 2; ++n) RD_FRAG(b23[n], Bb, brow + (2 + n) * 2048)

        // ---- stage ALL of tile t+1 (other buffer; t-1 reads fully retired)
        if (t < 7) {
            STAGE_A(t + 1, 0); STAGE_A(t + 1, 1);
            STAGE_B(t + 1, 0); STAGE_B(t + 1, 1);
        }

        // ---- Q1: alo x b01 (needs first 12 reads)
        asm volatile("s_waitcnt lgkmcnt(12)" ::: "memory");
        __builtin_amdgcn_sched_barrier(0);
        __builtin_amdgcn_s_setprio(1);
        MFMA_Q(0, alo, b01, 0);
        __builtin_amdgcn_s_setprio(0);
        // ---- Q2: ahi x b01 (needs first 20)
        asm volatile("s_waitcnt lgkmcnt(4)" ::: "memory");
        __builtin_amdgcn_sched_barrier(0);
        __builtin_amdgcn_s_setprio(1);
        MFMA_Q(4, ahi, b01, 0);
        __builtin_amdgcn_s_setprio(0);
        // ---- Q3+Q4: all reads retired
        asm volatile("s_waitcnt lgkmcnt(0)" ::: "memory");
        __builtin_amdgcn_sched_barrier(0);
        __builtin_amdgcn_s_setprio(1);
        MFMA_Q(4, ahi, b23, 2);
        MFMA_Q(0, alo, b23, 2);
        __builtin_amdgcn_s_setprio(0);

        // ---- tile end: next tile landed, publish buffers
        if (t < 7) { asm volatile("s_waitcnt vmcnt(0)" ::: "memory"); }
        __builtin_amdgcn_s_barrier();
        __builtin_amdgcn_sched_barrier(0);
    }

    // ---- epilogue: fused min over memory dim
    if (tid < 256) rowmin[tid] = 0xFFFFFFFFu;
    __syncthreads();

    float mb2v[4];
    #pragma unroll
    for (int n = 0; n < 4; ++n) mb2v[n] = mb2[m0 + wn * 64 + n * 16 + (lane & 15)];

    #pragma unroll
    for (int m = 0; m < 8; ++m) {
        #pragma unroll
        for (int r = 0; r < 4; ++r) {
            const int qrow = wm * 128 + m * 16 + (lane >> 4) * 4 + r;
            const float qq = qn2[q0 + qrow];
            float v = 3.4e38f;
            #pragma unroll
            for (int n = 0; n < 4; ++n) {
                float d2 = qq + mb2v[n] - 2.0f * acc[m][n][r];
                v = fminf(v, d2);
            }
            #pragma unroll
            for (int s = 1; s < 16; s <<= 1) v = fminf(v, __shfl_xor(v, s));
            if ((lane & 15) == 0) atomicMin(&rowmin[qrow], flipf(v));
        }
    }
    __syncthreads();
    if (tid < 256) atomicMin(minkeys + q0 + tid, rowmin[tid]);
}

// per-image max + write patch scores
__global__ __launch_bounds__(256) void final_kernel(const u32* __restrict__ keys, float* __restrict__ out) {
    int b = blockIdx.x, tid = threadIdx.x;
    float mx = -3.4e38f;
    for (int i = tid; i < 784; i += 256) {
        float f = unflipf(keys[b * 784 + i]);
        out[8 + b * 784 + i] = f;
        mx = fmaxf(mx, f);
    }
    for (int s = 32; s; s >>= 1) mx = fmaxf(mx, __shfl_down(mx, s));
    __shared__ float sm[4];
    if ((tid & 63) == 0) sm[tid >> 6] = mx;
    __syncthreads();
    if (tid == 0) out[b] = fmaxf(fmaxf(sm[0], sm[1]), fmaxf(sm[2], sm[3]));
}

extern "C" void kernel_launch(void* const* d_in, const int* in_sizes, int n_in,
                              void* d_out, int out_size, void* d_ws, size_t ws_size,
                              hipStream_t stream) {
    const float* feat2 = (const float*)d_in[0];   // [8,512,28,28]
    const float* feat3 = (const float*)d_in[1];   // [8,1024,14,14]
    const float* mb    = (const float*)d_in[2];   // [16384,1024]
    float* out = (float*)d_out;                   // [8] image + [8,28,28] patch

    char* ws = (char*)d_ws;
    float* U      = (float*)(ws);                  // 3,211,264 B
    u8*    qb     = (u8*)   (ws + 3211264);        // 6400*1024 = 6,553,600 B (pad rows unused)
    u8*    mbb    = (u8*)   (ws + 9764864);        // 16,777,216 B
    float* qn2    = (float*)(ws + 26542080);       // 25,088 B
    float* mb2    = (float*)(ws + 26567168);       // 65,536 B
    u32*   minkey = (u32*)  (ws + 26632704);       // 25,600 B

    prep_kernel<<<19520, 256, 0, stream>>>(feat3, U, mb, mbb, mb2, minkey);
    q_kernel<<<6272, 256, 0, stream>>>(feat2, U, qb, qn2);
    gemm_min_kernel<<<1600, 512, 0, stream>>>(qb, mbb, qn2, mb2, minkey);
    final_kernel<<<8, 256, 0, stream>>>(minkey, out);
}

// Round 9
// 861.152 us; speedup vs baseline: 1.4211x; 1.4211x over previous
//
#include <hip/hip_runtime.h>
#include <hip/hip_bf16.h>

typedef unsigned char u8;
typedef unsigned short u16;
typedef unsigned int u32;
typedef __attribute__((ext_vector_type(4))) int i32x4;
typedef __attribute__((ext_vector_type(8))) int i32x8;
typedef __attribute__((ext_vector_type(4))) float f32x4;

#define GLD16(g, l) __builtin_amdgcn_global_load_lds((const __attribute__((address_space(1))) u32*)(g), (__attribute__((address_space(3))) u32*)(l), 16, 0, 0)
#define SCALE1 0x7F7F7F7F   // E8M0 exponent 127 = 2^0 for all blocks

__device__ __forceinline__ u32 flipf(float f) {
    u32 u = __float_as_uint(f);
    return (u >> 31) ? ~u : (u | 0x80000000u);
}

__device__ __forceinline__ float unflipf(u32 k) {
    return __uint_as_float((k >> 31) ? (k ^ 0x80000000u) : ~k);
}

// pack 4 floats -> 4 fp8 e4m3 (OCP) bytes
__device__ __forceinline__ u32 pk4_fp8(float a, float b, float c, float d) {
    u32 r = (u32)__builtin_amdgcn_cvt_pk_fp8_f32(a, b, 0, false);
    r = (u32)__builtin_amdgcn_cvt_pk_fp8_f32(c, d, (int)r, true);
    return r;
}

// bilinear 14->28 taps (jax.image.resize, half-pixel, edge-renormalized)
__device__ __forceinline__ void taps(int o, int& i0, int& i1, float& w0, float& w1) {
    int k = (o - 1) >> 1;
    float fy = (0.5f * (float)o - 0.25f) - (float)k;
    i0 = k; i1 = k + 1;
    w0 = 1.0f - fy; w1 = fy;
    if (i0 < 0)  { i0 = 0;  w0 = 0.0f; w1 = 1.0f; }
    if (i1 > 13) { i1 = 13; w1 = 0.0f; w0 = 1.0f; }
}

// merged: [blocks 0..16383] memory-bank fp32->fp8 + norms (+minkey init)
//         [blocks 16384..19519] U = 3x3 box-sum of paired feat3 channels
__global__ __launch_bounds__(256) void prep_kernel(
    const float* __restrict__ f3, float* __restrict__ U,
    const float* __restrict__ mb, u8* __restrict__ mbb, float* __restrict__ mb2,
    u32* __restrict__ minkey) {
    int bid = blockIdx.x, tid = threadIdx.x;
    if (bid < 16384) {
        float4 v = ((const float4*)(mb + (size_t)bid * 1024))[tid];
        ((u32*)(mbb + (size_t)bid * 1024))[tid] = pk4_fp8(v.x, v.y, v.z, v.w);
        float ssq = v.x * v.x + v.y * v.y + v.z * v.z + v.w * v.w;
        for (int s = 32; s; s >>= 1) ssq += __shfl_down(ssq, s);
        __shared__ float sm[4];
        if ((tid & 63) == 0) sm[tid >> 6] = ssq;
        __syncthreads();
        if (tid == 0) mb2[bid] = sm[0] + sm[1] + sm[2] + sm[3];
        if (bid < 25) {
            int i = bid * 256 + tid;
            if (i < 6400) minkey[i] = 0xFFFFFFFFu;
        }
    } else {
        int idx = (bid - 16384) * 256 + tid;
        if (idx >= 8 * 512 * 196) return;
        int b = idx / (512 * 196);
        int rem = idx % (512 * 196);
        int t = rem / 196;
        int yx = rem % 196;
        int y = yx / 14, x = yx % 14;
        const float* p0 = f3 + ((size_t)(b * 1024 + 2 * t)) * 196;
        const float* p1 = p0 + 196;
        float s = 0.f;
        #pragma unroll
        for (int dy = -1; dy <= 1; ++dy) {
            int yy = y + dy; if ((unsigned)yy >= 14u) continue;
            #pragma unroll
            for (int dx = -1; dx <= 1; ++dx) {
                int xx = x + dx; if ((unsigned)xx >= 14u) continue;
                s += p0[yy * 14 + xx] + p1[yy * 14 + xx];
            }
        }
        U[idx] = s;
    }
}

// q[n, 0:512] = weighted 3x3 mean of feat2; q[n, 512+t] = bilinear(U)[h,w]/18
// thread handles 4 CONSECUTIVE dims -> one packed u32 fp8 store.
__global__ __launch_bounds__(256) void q_kernel(const float* __restrict__ feat2, const float* __restrict__ U,
                                                u8* __restrict__ qb, float* __restrict__ qn2) {
    int n = blockIdx.x;
    int b = n / 784;
    int hw = n % 784;
    int h = hw / 28, w = hw % 28;
    int tid = threadIdx.x;
    int y0, y1, x0, x1; float wy0, wy1, wx0, wx1;
    taps(h, y0, y1, wy0, wy1);
    taps(w, x0, x1, wx0, wx1);
    int d0 = tid * 4;
    float vals[4];
    if (d0 < 512) {
        #pragma unroll
        for (int j = 0; j < 4; ++j) {
            const float* p = feat2 + ((size_t)(b * 512 + d0 + j)) * 784;
            float s = 0.f;
            #pragma unroll
            for (int di = -1; di <= 1; ++di) {
                int y = h + di; if ((unsigned)y >= 28u) continue;
                #pragma unroll
                for (int dj = -1; dj <= 1; ++dj) {
                    int x = w + dj; if ((unsigned)x >= 28u) continue;
                    float v = p[y * 28 + x];
                    s += (di == 0 && dj == 0) ? 2.f * v : v;
                }
            }
            vals[j] = s * 0.1f;
        }
    } else {
        #pragma unroll
        for (int j = 0; j < 4; ++j) {
            const float* up = U + ((size_t)(b * 512 + (d0 - 512 + j))) * 196;
            float v00 = up[y0 * 14 + x0], v01 = up[y0 * 14 + x1];
            float v10 = up[y1 * 14 + x0], v11 = up[y1 * 14 + x1];
            vals[j] = (wy0 * (wx0 * v00 + wx1 * v01) + wy1 * (wx0 * v10 + wx1 * v11)) * (1.f / 18.f);
        }
    }
    ((u32*)(qb + (size_t)n * 1024))[tid] = pk4_fp8(vals[0], vals[1], vals[2], vals[3]);
    float ssq = vals[0] * vals[0] + vals[1] * vals[1] + vals[2] * vals[2] + vals[3] * vals[3];
    for (int s = 32; s; s >>= 1) ssq += __shfl_down(ssq, s);
    __shared__ float sm[4];
    if ((tid & 63) == 0) sm[tid >> 6] = ssq;
    __syncthreads();
    if (tid == 0) qn2[n] = sm[0] + sm[1] + sm[2] + sm[3];
}

// 128x256-tile BK=128 FP8 MX GEMM (mfma_scale_f32_16x16x128_f8f6f4, scales=1).
// Per-wave tile 64x64: acc 64 regs + 8 i32x8 frags 64 regs -> NO spill (R8 fix).
// Burst schedule: 16 frag ds_reads + 6 next-tile gld16 up front, lgkmcnt(4)/(0)
// gates, 1 barrier + 1 vmcnt per tile. Fused min epilogue.
// M=6400 (q rows, 6272 real), N=16384, K=1024 -> 8 K-tiles.
__global__ __launch_bounds__(512, 1) void gemm_min_kernel(
    const u8* __restrict__ qb, const u8* __restrict__ mbb,
    const float* __restrict__ qn2, const float* __restrict__ mb2,
    u32* __restrict__ minkeys) {
    __shared__ __align__(16) u8 As[2][16384];   // [buf][128 rows x 128 B]
    __shared__ __align__(16) u8 Bs[2][32768];   // [buf][256 rows x 128 B]
    __shared__ u32 rowmin[128];

    const int tid = threadIdx.x;
    const int wid = tid >> 6;
    const int lane = tid & 63;
    const int wm = wid >> 2;   // 2 M-waves (64 rows each)
    const int wn = wid & 3;    // 4 N-waves (64 cols each)

    // XCD-aware bijective swizzle: 3200 blocks, 8 XCDs, 400/XCD.
    const int flat = blockIdx.x;
    const int swz = (flat & 7) * 400 + (flat >> 3);
    const int q0 = (swz % 50) * 128;   // q-row (M) panel
    const int m0 = (swz / 50) * 256;   // memory-bank (N) panel

    // staging: instr j of wave covers LDS rows wid*8 + j*64 (8 rows = 1KB).
    // LDS dest linear; global source 16B-slot XOR-swizzled with row&7.
    const int rloc = wid * 8 + (lane >> 3);           // + j*64
    const int srcslot = (lane & 7) ^ (lane >> 3);
    size_t baseA[2], baseB[4];
    u32 ldst[4];
    #pragma unroll
    for (int j = 0; j < 4; ++j) {
        if (j < 2) baseA[j] = (size_t)(q0 + rloc + j * 64) * 1024 + srcslot * 16;
        baseB[j] = (size_t)(m0 + rloc + j * 64) * 1024 + srcslot * 16;
        ldst[j] = wid * 1024 + j * 8192;              // byte idx, wave-uniform
    }

    #define STAGE_A(T) { const int _t = (T); \
        GLD16(qb + baseA[0] + _t * 128, &As[_t & 1][ldst[0]]); \
        GLD16(qb + baseA[1] + _t * 128, &As[_t & 1][ldst[1]]); }
    #define STAGE_B(T) { const int _t = (T); \
        GLD16(mbb + baseB[0] + _t * 128, &Bs[_t & 1][ldst[0]]); \
        GLD16(mbb + baseB[1] + _t * 128, &Bs[_t & 1][ldst[1]]); \
        GLD16(mbb + baseB[2] + _t * 128, &Bs[_t & 1][ldst[2]]); \
        GLD16(mbb + baseB[3] + _t * 128, &Bs[_t & 1][ldst[3]]); }

    // fragment read addressing (byte offsets; row&7 == lane&7 for all frags)
    const u32 arow = (u32)(wm * 64 + (lane & 15)) * 128;   // + m*2048
    const u32 brow = (u32)(wn * 64 + (lane & 15)) * 128;   // + n*2048
    const u32 sl0 = (u32)((((lane >> 4) * 2 + 0) ^ (lane & 7)) * 16);  // k bytes 0-15 of lane's 32
    const u32 sl1 = (u32)((((lane >> 4) * 2 + 1) ^ (lane & 7)) * 16);  // k bytes 16-31

    #define RD_FRAG(DST, BASE, OFF) { \
        i32x4 _lo = *(const i32x4*)((BASE) + (OFF) + sl0); \
        i32x4 _hi = *(const i32x4*)((BASE) + (OFF) + sl1); \
        DST = __builtin_shufflevector(_lo, _hi, 0, 1, 2, 3, 4, 5, 6, 7); }

    f32x4 acc[4][4] = {};
    i32x8 a[4], b[4];

    // ---- prologue: stage tile 0, wait, barrier
    STAGE_A(0); STAGE_B(0);
    asm volatile("s_waitcnt vmcnt(0)" ::: "memory");
    __builtin_amdgcn_s_barrier();
    __builtin_amdgcn_sched_barrier(0);

    for (int t = 0; t < 8; ++t) {
        const u8* Ab = &As[t & 1][0];
        const u8* Bb = &Bs[t & 1][0];

        // ---- burst: all 16 frag reads, order a0-3 (8), b01 (4), b23 (4)
        #pragma unroll
        for (int m = 0; m < 4; ++m) RD_FRAG(a[m], Ab, arow + m * 2048)
        #pragma unroll
        for (int n = 0; n < 4; ++n) RD_FRAG(b[n], Bb, brow + n * 2048)

        // ---- stage ALL of tile t+1 (other buffer; t-1 reads fully retired)
        if (t < 7) { STAGE_A(t + 1) STAGE_B(t + 1) }

        // ---- H1: a x b01 (needs first 12 reads); all 8 accs independent
        asm volatile("s_waitcnt lgkmcnt(4)" ::: "memory");
        __builtin_amdgcn_sched_barrier(0);
        __builtin_amdgcn_s_setprio(1);
        #pragma unroll
        for (int m = 0; m < 4; ++m)
            #pragma unroll
            for (int n = 0; n < 2; ++n)
                acc[m][n] = __builtin_amdgcn_mfma_scale_f32_16x16x128_f8f6f4(
                    a[m], b[n], acc[m][n], 0, 0, 0, SCALE1, 0, SCALE1);
        __builtin_amdgcn_s_setprio(0);
        // ---- H2: a x b23 (all reads retired)
        asm volatile("s_waitcnt lgkmcnt(0)" ::: "memory");
        __builtin_amdgcn_sched_barrier(0);
        __builtin_amdgcn_s_setprio(1);
        #pragma unroll
        for (int m = 0; m < 4; ++m)
            #pragma unroll
            for (int n = 2; n < 4; ++n)
                acc[m][n] = __builtin_amdgcn_mfma_scale_f32_16x16x128_f8f6f4(
                    a[m], b[n], acc[m][n], 0, 0, 0, SCALE1, 0, SCALE1);
        __builtin_amdgcn_s_setprio(0);

        // ---- tile end: next tile landed, publish buffers
        if (t < 7) { asm volatile("s_waitcnt vmcnt(0)" ::: "memory"); }
        __builtin_amdgcn_s_barrier();
        __builtin_amdgcn_sched_barrier(0);
    }

    // ---- epilogue: fused min over memory dim
    if (tid < 128) rowmin[tid] = 0xFFFFFFFFu;
    __syncthreads();

    float mb2v[4];
    #pragma unroll
    for (int n = 0; n < 4; ++n) mb2v[n] = mb2[m0 + wn * 64 + n * 16 + (lane & 15)];

    #pragma unroll
    for (int m = 0; m < 4; ++m) {
        #pragma unroll
        for (int r = 0; r < 4; ++r) {
            const int qrow = wm * 64 + m * 16 + (lane >> 4) * 4 + r;
            const float qq = qn2[q0 + qrow];
            float v = 3.4e38f;
            #pragma unroll
            for (int n = 0; n < 4; ++n) {
                float d2 = qq + mb2v[n] - 2.0f * acc[m][n][r];
                v = fminf(v, d2);
            }
            #pragma unroll
            for (int s = 1; s < 16; s <<= 1) v = fminf(v, __shfl_xor(v, s));
            if ((lane & 15) == 0) atomicMin(&rowmin[qrow], flipf(v));
        }
    }
    __syncthreads();
    if (tid < 128) atomicMin(minkeys + q0 + tid, rowmin[tid]);
}

// per-image max + write patch scores
__global__ __launch_bounds__(256) void final_kernel(const u32* __restrict__ keys, float* __restrict__ out) {
    int b = blockIdx.x, tid = threadIdx.x;
    float mx = -3.4e38f;
    for (int i = tid; i < 784; i += 256) {
        float f = unflipf(keys[b * 784 + i]);
        out[8 + b * 784 + i] = f;
        mx = fmaxf(mx, f);
    }
    for (int s = 32; s; s >>= 1) mx = fmaxf(mx, __shfl_down(mx, s));
    __shared__ float sm[4];
    if ((tid & 63) == 0) sm[tid >> 6] = mx;
    __syncthreads();
    if (tid == 0) out[b] = fmaxf(fmaxf(sm[0], sm[1]), fmaxf(sm[2], sm[3]));
}

extern "C" void kernel_launch(void* const* d_in, const int* in_sizes, int n_in,
                              void* d_out, int out_size, void* d_ws, size_t ws_size,
                              hipStream_t stream) {
    const float* feat2 = (const float*)d_in[0];   // [8,512,28,28]
    const float* feat3 = (const float*)d_in[1];   // [8,1024,14,14]
    const float* mb    = (const float*)d_in[2];   // [16384,1024]
    float* out = (float*)d_out;                   // [8] image + [8,28,28] patch

    char* ws = (char*)d_ws;
    float* U      = (float*)(ws);                  // 3,211,264 B
    u8*    qb     = (u8*)   (ws + 3211264);        // 6400*1024 = 6,553,600 B (pad rows unused)
    u8*    mbb    = (u8*)   (ws + 9764864);        // 16,777,216 B
    float* qn2    = (float*)(ws + 26542080);       // 25,088 B
    float* mb2    = (float*)(ws + 26567168);       // 65,536 B
    u32*   minkey = (u32*)  (ws + 26632704);       // 25,600 B

    prep_kernel<<<19520, 256, 0, stream>>>(feat3, U, mb, mbb, mb2, minkey);
    q_kernel<<<6272, 256, 0, stream>>>(feat2, U, qb, qn2);
    gemm_min_kernel<<<3200, 512, 0, stream>>>(qb, mbb, qn2, mb2, minkey);
    final_kernel<<<8, 256, 0, stream>>>(minkey, out);
}

// Round 10
// 386.880 us; speedup vs baseline: 3.1633x; 2.2259x over previous
//
#include <hip/hip_runtime.h>
#include <hip/hip_bf16.h>

typedef unsigned short u16;
typedef unsigned int u32;
typedef __attribute__((ext_vector_type(8))) __bf16 bf16x8;
typedef __attribute__((ext_vector_type(4))) float f32x4;

#define GLD16(g, l) __builtin_amdgcn_global_load_lds((const __attribute__((address_space(1))) u32*)(g), (__attribute__((address_space(3))) u32*)(l), 16, 0, 0)

__device__ __forceinline__ u16 f2bf(float f) {
    u32 u = __float_as_uint(f);
    u += 0x7FFFu + ((u >> 16) & 1u);
    return (u16)(u >> 16);
}

__device__ __forceinline__ u32 flipf(float f) {
    u32 u = __float_as_uint(f);
    return (u >> 31) ? ~u : (u | 0x80000000u);
}

__device__ __forceinline__ float unflipf(u32 k) {
    return __uint_as_float((k >> 31) ? (k ^ 0x80000000u) : ~k);
}

// bilinear 14->28 taps (jax.image.resize, half-pixel, edge-renormalized)
__device__ __forceinline__ void taps(int o, int& i0, int& i1, float& w0, float& w1) {
    int k = (o - 1) >> 1;
    float fy = (0.5f * (float)o - 0.25f) - (float)k;
    i0 = k; i1 = k + 1;
    w0 = 1.0f - fy; w1 = fy;
    if (i0 < 0)  { i0 = 0;  w0 = 0.0f; w1 = 1.0f; }
    if (i1 > 13) { i1 = 13; w1 = 0.0f; w0 = 1.0f; }
}

// merged: [blocks 0..16383] memory-bank fp32->bf16 + norms (+minkey init)
//         [blocks 16384..19519] U = 3x3 box-sum of paired feat3 channels
__global__ __launch_bounds__(256) void prep_kernel(
    const float* __restrict__ f3, float* __restrict__ U,
    const float* __restrict__ mb, u16* __restrict__ mbb, float* __restrict__ mb2,
    u32* __restrict__ minkey) {
    int bid = blockIdx.x, tid = threadIdx.x;
    if (bid < 16384) {
        float4 v = ((const float4*)(mb + (size_t)bid * 1024))[tid];
        ushort4 o;
        o.x = f2bf(v.x); o.y = f2bf(v.y); o.z = f2bf(v.z); o.w = f2bf(v.w);
        ((ushort4*)(mbb + (size_t)bid * 1024))[tid] = o;
        float ssq = v.x * v.x + v.y * v.y + v.z * v.z + v.w * v.w;
        for (int s = 32; s; s >>= 1) ssq += __shfl_down(ssq, s);
        __shared__ float sm[4];
        if ((tid & 63) == 0) sm[tid >> 6] = ssq;
        __syncthreads();
        if (tid == 0) mb2[bid] = sm[0] + sm[1] + sm[2] + sm[3];
        if (bid < 25) {
            int i = bid * 256 + tid;
            if (i < 6400) minkey[i] = 0xFFFFFFFFu;
        }
    } else {
        int idx = (bid - 16384) * 256 + tid;
        if (idx >= 8 * 512 * 196) return;
        int b = idx / (512 * 196);
        int rem = idx % (512 * 196);
        int t = rem / 196;
        int yx = rem % 196;
        int y = yx / 14, x = yx % 14;
        const float* p0 = f3 + ((size_t)(b * 1024 + 2 * t)) * 196;
        const float* p1 = p0 + 196;
        float s = 0.f;
        #pragma unroll
        for (int dy = -1; dy <= 1; ++dy) {
            int yy = y + dy; if ((unsigned)yy >= 14u) continue;
            #pragma unroll
            for (int dx = -1; dx <= 1; ++dx) {
                int xx = x + dx; if ((unsigned)xx >= 14u) continue;
                s += p0[yy * 14 + xx] + p1[yy * 14 + xx];
            }
        }
        U[idx] = s;
    }
}

// q[n, 0:512] = weighted 3x3 mean of feat2; q[n, 512+t] = bilinear(U)[h,w]/18
__global__ __launch_bounds__(256) void q_kernel(const float* __restrict__ feat2, const float* __restrict__ U,
                                                u16* __restrict__ qb, float* __restrict__ qn2) {
    int n = blockIdx.x;
    int b = n / 784;
    int hw = n % 784;
    int h = hw / 28, w = hw % 28;
    int tid = threadIdx.x;
    int y0, y1, x0, x1; float wy0, wy1, wx0, wx1;
    taps(h, y0, y1, wy0, wy1);
    taps(w, x0, x1, wx0, wx1);
    float ssq = 0.f;
    #pragma unroll
    for (int k = 0; k < 4; ++k) {
        int d = tid + k * 256;
        float val;
        if (d < 512) {
            const float* p = feat2 + ((size_t)(b * 512 + d)) * 784;
            float s = 0.f;
            #pragma unroll
            for (int di = -1; di <= 1; ++di) {
                int y = h + di; if ((unsigned)y >= 28u) continue;
                #pragma unroll
                for (int dj = -1; dj <= 1; ++dj) {
                    int x = w + dj; if ((unsigned)x >= 28u) continue;
                    float v = p[y * 28 + x];
                    s += (di == 0 && dj == 0) ? 2.f * v : v;
                }
            }
            val = s * 0.1f;
        } else {
            const float* up = U + ((size_t)(b * 512 + (d - 512))) * 196;
            float v00 = up[y0 * 14 + x0], v01 = up[y0 * 14 + x1];
            float v10 = up[y1 * 14 + x0], v11 = up[y1 * 14 + x1];
            val = (wy0 * (wx0 * v00 + wx1 * v01) + wy1 * (wx0 * v10 + wx1 * v11)) * (1.f / 18.f);
        }
        ssq += val * val;
        qb[(size_t)n * 1024 + d] = f2bf(val);
    }
    for (int s = 32; s; s >>= 1) ssq += __shfl_down(ssq, s);
    __shared__ float sm[4];
    if ((tid & 63) == 0) sm[tid >> 6] = ssq;
    __syncthreads();
    if (tid == 0) qn2[n] = sm[0] + sm[1] + sm[2] + sm[3];
}

// 128x256-tile BK=32 bf16 MFMA GEMM tuned for 2 BLOCKS/CU (the R3-R7 plateau
// was 1 block/CU convoy): LDS 48.5KB, per-wave 64x64 (acc 64 + frags 32 regs),
// __launch_bounds__(512,4) caps VGPR at 128 -> 16 waves/CU. R6 burst flow:
// all 8 frag reads + 3 staging GLD16 up front, lgkmcnt(2)/(0) gates,
// 1 barrier + 1 vmcnt per tile. Fused min epilogue.
// M=6400 (q rows, 6272 real), N=16384, K=1024 -> 32 K-tiles.
__global__ __launch_bounds__(512, 4) void gemm_min_kernel(
    const u16* __restrict__ qb, const u16* __restrict__ mbb,
    const float* __restrict__ qn2, const float* __restrict__ mb2,
    u32* __restrict__ minkeys) {
    __shared__ __align__(16) u16 As[2][4096];   // [buf][128 rows x 32 cols]
    __shared__ __align__(16) u16 Bs[2][8192];   // [buf][256 rows x 32 cols]
    __shared__ u32 rowmin[128];

    const int tid = threadIdx.x;
    const int wid = tid >> 6;
    const int lane = tid & 63;
    const int wm = wid >> 2;   // 2 M-waves (64 rows each)
    const int wn = wid & 3;    // 4 N-waves (64 cols each)

    // XCD-aware bijective swizzle: 3200 blocks, 8 XCDs, 400/XCD.
    const int flat = blockIdx.x;
    const int swz = (flat & 7) * 400 + (flat >> 3);
    const int q0 = (swz % 50) * 128;   // q-row (M) panel
    const int m0 = (swz / 50) * 256;   // memory-bank (N) panel

    // staging: rows of 32 u16 (64 B = 4 x 16B slots). One GLD16 = 8KB/block
    // (512 lanes x 16B) = 128 rows. LDS dest linear; global source slot
    // XOR-swizzled with (row>>1)&3 (row = wid*16 + (lane>>2)).
    const int rloc = wid * 16 + (lane >> 2);            // 0..127
    const int sslot = (lane & 3) ^ ((lane >> 3) & 3);   // source 16B slot
    const size_t gA  = (size_t)(q0 + rloc) * 1024 + sslot * 8;
    const size_t gB0 = (size_t)(m0 + rloc) * 1024 + sslot * 8;
    const size_t gB1 = (size_t)(m0 + 128 + rloc) * 1024 + sslot * 8;
    const u32 ldA = wid * 512;                 // u16 idx, wave-uniform
    const u32 ldB1 = 4096 + wid * 512;

    #define STAGE(T) { const int _t = (T); \
        GLD16(qb + gA + _t * 32, &As[_t & 1][ldA]); \
        GLD16(mbb + gB0 + _t * 32, &Bs[_t & 1][ldA]); \
        GLD16(mbb + gB1 + _t * 32, &Bs[_t & 1][ldB1]); }

    // fragment read addressing: row = base + (lane&15); slot = (lane>>4) ^ ((row>>1)&3)
    const u32 arow = (u32)(wm * 64 + (lane & 15)) * 32;   // + m*512
    const u32 brow = (u32)(wn * 64 + (lane & 15)) * 32;   // + n*512
    const u32 sl = (u32)(((lane >> 4) ^ (((lane & 15) >> 1) & 3)) * 8);

    f32x4 acc[4][4] = {};
    bf16x8 a[4], b[4];

    // ---- prologue: stage tile 0, wait, barrier
    STAGE(0);
    asm volatile("s_waitcnt vmcnt(0)" ::: "memory");
    __builtin_amdgcn_s_barrier();
    __builtin_amdgcn_sched_barrier(0);

    for (int t = 0; t < 32; ++t) {
        const u16* Ab = &As[t & 1][0];
        const u16* Bb = &Bs[t & 1][0];

        // ---- burst: all 8 frag reads (order a0-3, b0-3)
        #pragma unroll
        for (int m = 0; m < 4; ++m) a[m] = *(const bf16x8*)&Ab[arow + m * 512 + sl];
        #pragma unroll
        for (int n = 0; n < 4; ++n) b[n] = *(const bf16x8*)&Bb[brow + n * 512 + sl];

        // ---- stage tile t+1 (other buffer; t-1 reads retired at t-1 end barrier)
        if (t < 31) STAGE(t + 1)

        // ---- H1: a x b01 (needs a0-3 + b0,b1; b2,b3 may be outstanding)
        asm volatile("s_waitcnt lgkmcnt(2)" ::: "memory");
        __builtin_amdgcn_sched_barrier(0);
        __builtin_amdgcn_s_setprio(1);
        #pragma unroll
        for (int m = 0; m < 4; ++m)
            #pragma unroll
            for (int n = 0; n < 2; ++n)
                acc[m][n] = __builtin_amdgcn_mfma_f32_16x16x32_bf16(a[m], b[n], acc[m][n], 0, 0, 0);
        __builtin_amdgcn_s_setprio(0);
        // ---- H2: a x b23
        asm volatile("s_waitcnt lgkmcnt(0)" ::: "memory");
        __builtin_amdgcn_sched_barrier(0);
        __builtin_amdgcn_s_setprio(1);
        #pragma unroll
        for (int m = 0; m < 4; ++m)
            #pragma unroll
            for (int n = 2; n < 4; ++n)
                acc[m][n] = __builtin_amdgcn_mfma_f32_16x16x32_bf16(a[m], b[n], acc[m][n], 0, 0, 0);
        __builtin_amdgcn_s_setprio(0);

        // ---- tile end: next tile landed, publish buffers
        if (t < 31) { asm volatile("s_waitcnt vmcnt(0)" ::: "memory"); }
        __builtin_amdgcn_s_barrier();
        __builtin_amdgcn_sched_barrier(0);
    }

    // ---- epilogue: fused min over memory dim
    if (tid < 128) rowmin[tid] = 0xFFFFFFFFu;
    __syncthreads();

    float mb2v[4];
    #pragma unroll
    for (int n = 0; n < 4; ++n) mb2v[n] = mb2[m0 + wn * 64 + n * 16 + (lane & 15)];

    #pragma unroll
    for (int m = 0; m < 4; ++m) {
        #pragma unroll
        for (int r = 0; r < 4; ++r) {
            const int qrow = wm * 64 + m * 16 + (lane >> 4) * 4 + r;
            const float qq = qn2[q0 + qrow];
            float v = 3.4e38f;
            #pragma unroll
            for (int n = 0; n < 4; ++n) {
                float d2 = qq + mb2v[n] - 2.0f * acc[m][n][r];
                v = fminf(v, d2);
            }
            #pragma unroll
            for (int s = 1; s < 16; s <<= 1) v = fminf(v, __shfl_xor(v, s));
            if ((lane & 15) == 0) atomicMin(&rowmin[qrow], flipf(v));
        }
    }
    __syncthreads();
    if (tid < 128) atomicMin(minkeys + q0 + tid, rowmin[tid]);
}

// per-image max + write patch scores
__global__ __launch_bounds__(256) void final_kernel(const u32* __restrict__ keys, float* __restrict__ out) {
    int b = blockIdx.x, tid = threadIdx.x;
    float mx = -3.4e38f;
    for (int i = tid; i < 784; i += 256) {
        float f = unflipf(keys[b * 784 + i]);
        out[8 + b * 784 + i] = f;
        mx = fmaxf(mx, f);
    }
    for (int s = 32; s; s >>= 1) mx = fmaxf(mx, __shfl_down(mx, s));
    __shared__ float sm[4];
    if ((tid & 63) == 0) sm[tid >> 6] = mx;
    __syncthreads();
    if (tid == 0) out[b] = fmaxf(fmaxf(sm[0], sm[1]), fmaxf(sm[2], sm[3]));
}

extern "C" void kernel_launch(void* const* d_in, const int* in_sizes, int n_in,
                              void* d_out, int out_size, void* d_ws, size_t ws_size,
                              hipStream_t stream) {
    const float* feat2 = (const float*)d_in[0];   // [8,512,28,28]
    const float* feat3 = (const float*)d_in[1];   // [8,1024,14,14]
    const float* mb    = (const float*)d_in[2];   // [16384,1024]
    float* out = (float*)d_out;                   // [8] image + [8,28,28] patch

    char* ws = (char*)d_ws;
    float* U      = (float*)(ws);                  // 3,211,264 B
    u16*   qb     = (u16*)  (ws + 3211264);        // 6400*1024*2 = 13,107,200 B (pad rows unused)
    u16*   mbb    = (u16*)  (ws + 16318464);       // 33,554,432 B
    float* qn2    = (float*)(ws + 49872896);       // 25,088 B
    float* mb2    = (float*)(ws + 49897984);       // 65,536 B
    u32*   minkey = (u32*)  (ws + 49963520);       // 25,600 B

    prep_kernel<<<19520, 256, 0, stream>>>(feat3, U, mb, mbb, mb2, minkey);
    q_kernel<<<6272, 256, 0, stream>>>(feat2, U, qb, qn2);
    gemm_min_kernel<<<3200, 512, 0, stream>>>(qb, mbb, qn2, mb2, minkey);
    final_kernel<<<8, 256, 0, stream>>>(minkey, out);
}